// Round 1
// baseline (299.481 us; speedup 1.0000x reference)
//
#include <hip/hip_runtime.h>

#define NN 2048
#define DD 128
#define EE 16384

// ---------------------------------------------------------------------------
// Stage 1: u[d] = sum_k W2[0, D+k] * W1[k, d]   (the only part of W1/W2 that
// survives the softmax cancellation), then e[n] = exp(X_n[n,:] . u).
// Grid: 128 blocks x 256 threads; each block redundantly computes u (16K MACs)
// into LDS, then its 4 waves each produce 4 rows' e values via shfl-reduce.
// ---------------------------------------------------------------------------
__global__ void k_sj(const float* __restrict__ X, const float* __restrict__ W1,
                     const float* __restrict__ W2, float* __restrict__ ev) {
    __shared__ float u[DD];
    const int t = threadIdx.x;  // 256
    if (t < DD) {
        float acc = 0.f;
#pragma unroll 8
        for (int k = 0; k < DD; ++k) acc += W2[DD + k] * W1[k * DD + t];
        u[t] = acc;
    }
    __syncthreads();
    const int wave = t >> 6, lane = t & 63;
    const int row0 = blockIdx.x * 16 + wave * 4;
#pragma unroll
    for (int rr = 0; rr < 4; ++rr) {
        const int row = row0 + rr;
        const float2 v = ((const float2*)(X + (size_t)row * DD))[lane];
        float acc = v.x * u[2 * lane] + v.y * u[2 * lane + 1];
#pragma unroll
        for (int off = 32; off; off >>= 1) acc += __shfl_down(acc, off);
        if (lane == 0) ev[row] = expf(acc);
    }
}

// ---------------------------------------------------------------------------
// Stage 2: Z[i] = sum_j adj[i,j] * e[j]   (adj is {0,1} so multiply, no branch)
// One block (256 threads) per row; int4 adj loads + float4 e loads, 2 iters.
// ---------------------------------------------------------------------------
__global__ void k_rowz(const int* __restrict__ adj, const float* __restrict__ ev,
                       float* __restrict__ Zv) {
    const int i = blockIdx.x;
    const int t = threadIdx.x;  // 256
    const int4* arow = (const int4*)(adj + (size_t)i * NN);
    const float4* ef = (const float4*)ev;
    float acc = 0.f;
#pragma unroll
    for (int b = 0; b < NN / 4; b += 256) {
        const int4   a  = arow[b + t];
        const float4 e4 = ef[b + t];
        acc += (float)a.x * e4.x + (float)a.y * e4.y +
               (float)a.z * e4.z + (float)a.w * e4.w;
    }
#pragma unroll
    for (int off = 32; off; off >>= 1) acc += __shfl_down(acc, off);
    __shared__ float wsum[4];
    if ((t & 63) == 0) wsum[t >> 6] = acc;
    __syncthreads();
    if (t == 0) Zv[i] = wsum[0] + wsum[1] + wsum[2] + wsum[3];
}

// ---------------------------------------------------------------------------
// Stage 3: scatter the 2E requested attention values into the zeroed output.
// a_p[e] = attention[dst,src] -> out[dst*2E + e]
// a_c[e] = attention[src,dst] -> out[src*2E + E + e]
// attention[i,j] = Z[i]==0 ? 1/N : (adj[i,j] ? e[j]/Z[i] : 0)
// ---------------------------------------------------------------------------
__global__ void k_edge(const int* __restrict__ ei, const int* __restrict__ adj,
                       const float* __restrict__ ev, const float* __restrict__ Zv,
                       float* __restrict__ out) {
    const int e = blockIdx.x * blockDim.x + threadIdx.x;
    if (e >= EE) return;
    const int s = ei[e];        // edge_indices[0] = src
    const int d = ei[EE + e];   // edge_indices[1] = dst
    const float invn = 1.0f / (float)NN;

    const float zd = Zv[d];
    float ap;
    if (zd == 0.f) ap = invn;
    else ap = (adj[(size_t)d * NN + s] > 0) ? ev[s] / zd : 0.f;
    out[(size_t)d * (2 * EE) + e] = ap;

    const float zs = Zv[s];
    float ac;
    if (zs == 0.f) ac = invn;
    else ac = (adj[(size_t)s * NN + d] > 0) ? ev[d] / zs : 0.f;
    out[(size_t)s * (2 * EE) + EE + e] = ac;
}

extern "C" void kernel_launch(void* const* d_in, const int* in_sizes, int n_in,
                              void* d_out, int out_size, void* d_ws, size_t ws_size,
                              hipStream_t stream) {
    const float* X   = (const float*)d_in[0];
    const int*   ei  = (const int*)d_in[1];
    const int*   adj = (const int*)d_in[2];
    const float* W1  = (const float*)d_in[3];
    const float* W2  = (const float*)d_in[4];
    float* out = (float*)d_out;

    float* ev = (float*)d_ws;   // e[j] = exp(s_j[j])   [2048]
    float* Zv = ev + NN;        // Z[i]                 [2048]

    // Output is ~all zeros (only 2E of N*2E entries are set). Zero it first;
    // this 256 MB write is the roofline for the whole problem.
    hipMemsetAsync(d_out, 0, (size_t)out_size * sizeof(float), stream);

    k_sj  <<<NN / 16, 256, 0, stream>>>(X, W1, W2, ev);
    k_rowz<<<NN,      256, 0, stream>>>(adj, ev, Zv);
    k_edge<<<EE / 256, 256, 0, stream>>>(ei, adj, ev, Zv, out);
}

// Round 2
// 294.690 us; speedup vs baseline: 1.0163x; 1.0163x over previous
//
#include <hip/hip_runtime.h>

#define NN 2048
#define DD 128
#define EE 16384

// ---------------------------------------------------------------------------
// Zero-fill the 256 MB output with wide stores. This replaces the opaque
// rocclr fillBufferAligned so the dispatch is visible/attributable in rocprof.
// 64M floats = 16M float4; 16384 blocks x 256 threads x 4 iters.
// ---------------------------------------------------------------------------
__global__ __launch_bounds__(256) void k_zero(float4* __restrict__ out4, int n4) {
    int i = blockIdx.x * blockDim.x + threadIdx.x;
    const int stride = gridDim.x * blockDim.x;
    const float4 z = make_float4(0.f, 0.f, 0.f, 0.f);
    for (; i < n4; i += stride) out4[i] = z;
}

// ---------------------------------------------------------------------------
// Stage 1: u[d] = sum_k W2[0, D+k] * W1[k, d]  (only surviving part of W1/W2
// after softmax cancellation: weight[i,j] = s_i[i]+s_j[j], s_i cancels in the
// row-softmax). Then e[n] = exp(X_n[n,:] . u).
// ---------------------------------------------------------------------------
__global__ void k_sj(const float* __restrict__ X, const float* __restrict__ W1,
                     const float* __restrict__ W2, float* __restrict__ ev) {
    __shared__ float u[DD];
    const int t = threadIdx.x;  // 256
    if (t < DD) {
        float acc = 0.f;
#pragma unroll 8
        for (int k = 0; k < DD; ++k) acc += W2[DD + k] * W1[k * DD + t];
        u[t] = acc;
    }
    __syncthreads();
    const int wave = t >> 6, lane = t & 63;
    const int row0 = blockIdx.x * 16 + wave * 4;
#pragma unroll
    for (int rr = 0; rr < 4; ++rr) {
        const int row = row0 + rr;
        const float2 v = ((const float2*)(X + (size_t)row * DD))[lane];
        float acc = v.x * u[2 * lane] + v.y * u[2 * lane + 1];
#pragma unroll
        for (int off = 32; off; off >>= 1) acc += __shfl_down(acc, off);
        if (lane == 0) ev[row] = expf(acc);
    }
}

// ---------------------------------------------------------------------------
// Stage 2: Z[i] = sum_j adj[i,j] * e[j]   (adj is {0,1}: multiply, no branch)
// ---------------------------------------------------------------------------
__global__ void k_rowz(const int* __restrict__ adj, const float* __restrict__ ev,
                       float* __restrict__ Zv) {
    const int i = blockIdx.x;
    const int t = threadIdx.x;  // 256
    const int4* arow = (const int4*)(adj + (size_t)i * NN);
    const float4* ef = (const float4*)ev;
    float acc = 0.f;
#pragma unroll
    for (int b = 0; b < NN / 4; b += 256) {
        const int4   a  = arow[b + t];
        const float4 e4 = ef[b + t];
        acc += (float)a.x * e4.x + (float)a.y * e4.y +
               (float)a.z * e4.z + (float)a.w * e4.w;
    }
#pragma unroll
    for (int off = 32; off; off >>= 1) acc += __shfl_down(acc, off);
    __shared__ float wsum[4];
    if ((t & 63) == 0) wsum[t >> 6] = acc;
    __syncthreads();
    if (t == 0) Zv[i] = wsum[0] + wsum[1] + wsum[2] + wsum[3];
}

// ---------------------------------------------------------------------------
// Stage 3: scatter the 2E requested attention values into the zeroed output.
// attention[i,j] = Z[i]==0 ? 1/N : (adj[i,j] ? e[j]/Z[i] : 0)
// ---------------------------------------------------------------------------
__global__ void k_edge(const int* __restrict__ ei, const int* __restrict__ adj,
                       const float* __restrict__ ev, const float* __restrict__ Zv,
                       float* __restrict__ out) {
    const int e = blockIdx.x * blockDim.x + threadIdx.x;
    if (e >= EE) return;
    const int s = ei[e];        // edge_indices[0] = src
    const int d = ei[EE + e];   // edge_indices[1] = dst
    const float invn = 1.0f / (float)NN;

    const float zd = Zv[d];
    float ap;
    if (zd == 0.f) ap = invn;
    else ap = (adj[(size_t)d * NN + s] > 0) ? ev[s] / zd : 0.f;
    out[(size_t)d * (2 * EE) + e] = ap;

    const float zs = Zv[s];
    float ac;
    if (zs == 0.f) ac = invn;
    else ac = (adj[(size_t)s * NN + d] > 0) ? ev[d] / zs : 0.f;
    out[(size_t)s * (2 * EE) + EE + e] = ac;
}

extern "C" void kernel_launch(void* const* d_in, const int* in_sizes, int n_in,
                              void* d_out, int out_size, void* d_ws, size_t ws_size,
                              hipStream_t stream) {
    const float* X   = (const float*)d_in[0];
    const int*   ei  = (const int*)d_in[1];
    const int*   adj = (const int*)d_in[2];
    const float* W1  = (const float*)d_in[3];
    const float* W2  = (const float*)d_in[4];
    float* out = (float*)d_out;

    float* ev = (float*)d_ws;   // e[j] = exp(s_j[j])   [2048]
    float* Zv = ev + NN;        // Z[i]                 [2048]

    // Output is ~all zeros (only 2E of N*2E entries are set). Custom wide-store
    // zero fill; this 256 MB write is the roofline for the whole problem.
    const int n4 = out_size / 4;  // float4 count
    k_zero<<<16384, 256, 0, stream>>>((float4*)out, n4);

    k_sj  <<<NN / 16, 256, 0, stream>>>(X, W1, W2, ev);
    k_rowz<<<NN,      256, 0, stream>>>(adj, ev, Zv);
    k_edge<<<EE / 256, 256, 0, stream>>>(ei, adj, ev, Zv, out);
}

// Round 3
// 292.516 us; speedup vs baseline: 1.0238x; 1.0074x over previous
//
#include <hip/hip_runtime.h>

#define NN 2048
#define DD 128
#define EE 16384

typedef float v4f __attribute__((ext_vector_type(4)));
typedef int   v4i __attribute__((ext_vector_type(4)));

// ---------------------------------------------------------------------------
// Stage 1: u[d] = sum_k W2[0, D+k] * W1[k, d]  (only surviving part of W1/W2
// after softmax cancellation: weight[i,j] = s_i[i]+s_j[j]; s_i is constant per
// row and cancels in the row-softmax). Then e[n] = exp(X_n[n,:] . u).
// ---------------------------------------------------------------------------
__global__ void k_sj(const float* __restrict__ X, const float* __restrict__ W1,
                     const float* __restrict__ W2, float* __restrict__ ev) {
    __shared__ float u[DD];
    const int t = threadIdx.x;  // 256
    if (t < DD) {
        float acc = 0.f;
#pragma unroll 8
        for (int k = 0; k < DD; ++k) acc += W2[DD + k] * W1[k * DD + t];
        u[t] = acc;
    }
    __syncthreads();
    const int wave = t >> 6, lane = t & 63;
    const int row0 = blockIdx.x * 16 + wave * 4;
#pragma unroll
    for (int rr = 0; rr < 4; ++rr) {
        const int row = row0 + rr;
        const float2 v = ((const float2*)(X + (size_t)row * DD))[lane];
        float acc = v.x * u[2 * lane] + v.y * u[2 * lane + 1];
#pragma unroll
        for (int off = 32; off; off >>= 1) acc += __shfl_down(acc, off);
        if (lane == 0) ev[row] = expf(acc);
    }
}

// ---------------------------------------------------------------------------
// Stage 2: Z[i] = sum_j adj[i,j] * e[j]   (adj is {0,1}: multiply, no branch)
// ---------------------------------------------------------------------------
__global__ void k_rowz(const int* __restrict__ adj, const float* __restrict__ ev,
                       float* __restrict__ Zv) {
    const int i = blockIdx.x;
    const int t = threadIdx.x;  // 256
    const int4* arow = (const int4*)(adj + (size_t)i * NN);
    const float4* ef = (const float4*)ev;
    float acc = 0.f;
#pragma unroll
    for (int b = 0; b < NN / 4; b += 256) {
        const int4   a  = arow[b + t];
        const float4 e4 = ef[b + t];
        acc += (float)a.x * e4.x + (float)a.y * e4.y +
               (float)a.z * e4.z + (float)a.w * e4.w;
    }
#pragma unroll
    for (int off = 32; off; off >>= 1) acc += __shfl_down(acc, off);
    __shared__ float wsum[4];
    if ((t & 63) == 0) wsum[t >> 6] = acc;
    __syncthreads();
    if (t == 0) Zv[i] = wsum[0] + wsum[1] + wsum[2] + wsum[3];
}

// ---------------------------------------------------------------------------
// Stage 3: per-edge values + the single nonzero row of each output column.
// Column c<E  : row dst[c], value a_p[c] = attention[dst,src]
// Column c>=E : row src[c], value a_c[c] = attention[src,dst]
// attention[i,j] = Z[i]==0 ? 1/N : (adj[i,j] ? e[j]/Z[i] : 0)
// c is the column index, so each column has exactly one writer (no dups).
// ---------------------------------------------------------------------------
__global__ void k_vals(const int* __restrict__ ei, const int* __restrict__ adj,
                       const float* __restrict__ ev, const float* __restrict__ Zv,
                       int* __restrict__ rowid, float* __restrict__ val) {
    const int e = blockIdx.x * blockDim.x + threadIdx.x;
    if (e >= EE) return;
    const int s = ei[e];        // edge_indices[0] = src
    const int d = ei[EE + e];   // edge_indices[1] = dst
    const float invn = 1.0f / (float)NN;

    const float zd = Zv[d];
    float ap;
    if (zd == 0.f) ap = invn;
    else ap = (adj[(size_t)d * NN + s] > 0) ? ev[s] / zd : 0.f;

    const float zs = Zv[s];
    float ac;
    if (zs == 0.f) ac = invn;
    else ac = (adj[(size_t)s * NN + d] > 0) ? ev[d] / zs : 0.f;

    rowid[e]      = d;  val[e]      = ap;
    rowid[EE + e] = s;  val[EE + e] = ac;
}

// ---------------------------------------------------------------------------
// Stage 4: single-pass output writer. Each thread owns one float4 of the
// [N, 2E] output; o = (rowid[c]==r) ? val[c] : 0, nontemporal store (written
// once, never re-read -> skip L2 pollution). rowid/val are 256 KB, L2-resident
// and broadcast across all 2048 rows.
// ---------------------------------------------------------------------------
__global__ __launch_bounds__(256) void k_write(const int* __restrict__ rowid,
                                               const float* __restrict__ val,
                                               v4f* __restrict__ out4) {
    const int l  = blockIdx.x * 256 + threadIdx.x;  // 0 .. 16M-1
    const int r  = l >> 13;        // row       (2E/4 = 8192 float4 per row)
    const int c4 = l & 8191;       // float4 column index
    const v4i rid = ((const v4i*)rowid)[c4];
    const v4f vv  = ((const v4f*)val)[c4];
    v4f o;
    o.x = (rid.x == r) ? vv.x : 0.f;
    o.y = (rid.y == r) ? vv.y : 0.f;
    o.z = (rid.z == r) ? vv.z : 0.f;
    o.w = (rid.w == r) ? vv.w : 0.f;
    __builtin_nontemporal_store(o, out4 + l);
}

extern "C" void kernel_launch(void* const* d_in, const int* in_sizes, int n_in,
                              void* d_out, int out_size, void* d_ws, size_t ws_size,
                              hipStream_t stream) {
    const float* X   = (const float*)d_in[0];
    const int*   ei  = (const int*)d_in[1];
    const int*   adj = (const int*)d_in[2];
    const float* W1  = (const float*)d_in[3];
    const float* W2  = (const float*)d_in[4];

    float* ev    = (float*)d_ws;          // [2048]  e[j] = exp(s_j[j])
    float* Zv    = ev + NN;               // [2048]
    float* val   = Zv + NN;               // [2*E]
    int*   rowid = (int*)(val + 2 * EE);  // [2*E]

    k_sj   <<<NN / 16,  256, 0, stream>>>(X, W1, W2, ev);
    k_rowz <<<NN,       256, 0, stream>>>(adj, ev, Zv);
    k_vals <<<EE / 256, 256, 0, stream>>>(ei, adj, ev, Zv, rowid, val);

    const int n4 = out_size / 4;          // 16,777,216 float4
    k_write<<<n4 / 256, 256, 0, stream>>>(rowid, val, (v4f*)d_out);
}